// Round 8
// baseline (236.860 us; speedup 1.0000x reference)
//
#include <hip/hip_runtime.h>
#include <hip/hip_fp16.h>

// MPA_16698832847132 — round 7: split conv pipeline into two kernels, each
// ~2 blocks/CU (cross-block latency hiding; the fused 163KB/1-block-per-CU
// design was barrier/latency-serialized at 9% MfmaUtil).
//  conv1_k: per (image, 17-row half) -> y1 to global (f16 channel-major).
//  conv2_k: per image; stats recomputed from staged f16 y1 (error ~1e-5 rel).
// Workspace: qkv bf16 @0 (25,165,824) | w f32 @25,165,824 (33,554,432)
//            y1g f16 @58,720,256 (75,759,616; ohb f32 16,777,216 overlays after)

typedef __attribute__((ext_vector_type(8))) short bf16x8;
typedef __attribute__((ext_vector_type(8))) _Float16 f16x8;
typedef __attribute__((ext_vector_type(4))) float f32x4;

__device__ __forceinline__ unsigned short f2bf(float f) {
  unsigned u = __builtin_bit_cast(unsigned, f);
  u += 0x7FFFu + ((u >> 16) & 1u);
  return (unsigned short)(u >> 16);
}

// ---------------- C[M][N] = A[M][K] * B[N][K]^T (+bias), f16 MFMA --------------
template<bool OUT_BF16>
__global__ __launch_bounds__(256) void gemm_f16_bt(
    const float* __restrict__ A, const float* __restrict__ B,
    void* __restrict__ Cv, const float* __restrict__ bias,
    int M, int N, int K)
{
  __shared__ __align__(16) _Float16 As[128 * 40];
  __shared__ __align__(16) _Float16 Bs[128 * 40];
  const int tid = threadIdx.x;
  const int wv = tid >> 6, ln = tid & 63, lr = ln & 15, lq = ln >> 4;
  const int wm = wv >> 1, wn = wv & 1;
  const int m0 = blockIdx.y * 128, n0 = blockIdx.x * 128;

  f32x4 acc[4][4];
#pragma unroll
  for (int i = 0; i < 4; i++)
#pragma unroll
    for (int j = 0; j < 4; j++) acc[i][j] = (f32x4){0.f, 0.f, 0.f, 0.f};

  const int sr = tid >> 1, sk = (tid & 1) * 16;
  const float* Ap = A + (size_t)(m0 + sr) * K + sk;
  const float* Bp = B + (size_t)(n0 + sr) * K + sk;

  for (int k0 = 0; k0 < K; k0 += 32) {
    float4 av0 = *(const float4*)(Ap + k0);
    float4 av1 = *(const float4*)(Ap + k0 + 4);
    float4 av2 = *(const float4*)(Ap + k0 + 8);
    float4 av3 = *(const float4*)(Ap + k0 + 12);
    float4 bv0 = *(const float4*)(Bp + k0);
    float4 bv1 = *(const float4*)(Bp + k0 + 4);
    float4 bv2 = *(const float4*)(Bp + k0 + 8);
    float4 bv3 = *(const float4*)(Bp + k0 + 12);
    __syncthreads();
    {
      f16x8 p0, p1, r0, r1;
      p0[0]=(_Float16)av0.x; p0[1]=(_Float16)av0.y; p0[2]=(_Float16)av0.z; p0[3]=(_Float16)av0.w;
      p0[4]=(_Float16)av1.x; p0[5]=(_Float16)av1.y; p0[6]=(_Float16)av1.z; p0[7]=(_Float16)av1.w;
      p1[0]=(_Float16)av2.x; p1[1]=(_Float16)av2.y; p1[2]=(_Float16)av2.z; p1[3]=(_Float16)av2.w;
      p1[4]=(_Float16)av3.x; p1[5]=(_Float16)av3.y; p1[6]=(_Float16)av3.z; p1[7]=(_Float16)av3.w;
      r0[0]=(_Float16)bv0.x; r0[1]=(_Float16)bv0.y; r0[2]=(_Float16)bv0.z; r0[3]=(_Float16)bv0.w;
      r0[4]=(_Float16)bv1.x; r0[5]=(_Float16)bv1.y; r0[6]=(_Float16)bv1.z; r0[7]=(_Float16)bv1.w;
      r1[0]=(_Float16)bv2.x; r1[1]=(_Float16)bv2.y; r1[2]=(_Float16)bv2.z; r1[3]=(_Float16)bv2.w;
      r1[4]=(_Float16)bv3.x; r1[5]=(_Float16)bv3.y; r1[6]=(_Float16)bv3.z; r1[7]=(_Float16)bv3.w;
      *(f16x8*)&As[sr * 40 + sk] = p0;
      *(f16x8*)&As[sr * 40 + sk + 8] = p1;
      *(f16x8*)&Bs[sr * 40 + sk] = r0;
      *(f16x8*)&Bs[sr * 40 + sk + 8] = r1;
    }
    __syncthreads();
    f16x8 af[4], bf[4];
#pragma unroll
    for (int mf = 0; mf < 4; mf++)
      af[mf] = *(const f16x8*)&As[(wm * 64 + mf * 16 + lr) * 40 + lq * 8];
#pragma unroll
    for (int nf = 0; nf < 4; nf++)
      bf[nf] = *(const f16x8*)&Bs[(wn * 64 + nf * 16 + lr) * 40 + lq * 8];
#pragma unroll
    for (int mf = 0; mf < 4; mf++)
#pragma unroll
      for (int nf = 0; nf < 4; nf++)
        acc[mf][nf] = __builtin_amdgcn_mfma_f32_16x16x32_f16(af[mf], bf[nf], acc[mf][nf], 0, 0, 0);
  }

#pragma unroll
  for (int mf = 0; mf < 4; mf++)
#pragma unroll
    for (int reg = 0; reg < 4; reg++) {
      const int row = m0 + wm * 64 + mf * 16 + lq * 4 + reg;
#pragma unroll
      for (int nf = 0; nf < 4; nf++) {
        const int col = n0 + wn * 64 + nf * 16 + lr;
        float v = acc[mf][nf][reg];
        if (bias) v += bias[col];
        if (OUT_BF16) ((unsigned short*)Cv)[(size_t)row * N + col] = f2bf(v);
        else          ((float*)Cv)[(size_t)row * N + col] = v;
      }
    }
}

// ---------------- conv1 (3x3, 32->32ch) -> y1 global, f16 MFMA -----------------
// grid 2048 = (img<<1)|half; 512 thr; LDS: inH[4][684][8] 43,776 + wH1 23,040 = 66,816 B.
// half h covers output rows h*17..h*17+16 (578 px), input rows h*17..h*17+18.
__global__ __launch_bounds__(512, 4) void conv1_k(
    const float* __restrict__ rpe, const float* __restrict__ c1w,
    unsigned short* __restrict__ y1g)
{
  extern __shared__ __align__(16) char smem[];
  unsigned short* inH = (unsigned short*)smem;            // 4 x 5472 halves
  unsigned short* wH1 = (unsigned short*)(smem + 43776);  // [tap*32 + ct*16 + r][40]

  const int tid = threadIdx.x;
  const int wv = tid >> 6, ln = tid & 63;
  const int lr = ln & 15, lq = ln >> 4;
  const int img = blockIdx.x >> 1, h = blockIdx.x & 1;

  // stage input band (19 rows = 684 px, channel-major groups)
  const float* src = rpe + (size_t)(((img >> 5) + 2) * 36 + (img & 31) + 2) * 41472
                   + h * 19584;
  for (int t = tid; t < 5472; t += 512) {
    int pix = t >> 3, dq = (t & 7) << 2;
    float4 v = *(const float4*)(src + t * 4);
    __half2 h0 = __floats2half2_rn(v.x, v.y);
    __half2 h1 = __floats2half2_rn(v.z, v.w);
    uint2 u; u.x = __builtin_bit_cast(unsigned, h0); u.y = __builtin_bit_cast(unsigned, h1);
    *(uint2*)&inH[(dq >> 3) * 5472 + pix * 8 + (dq & 7)] = u;
  }
  // stage weights (stride-40 rows, consumer order)
  for (int t = tid; t < 9216; t += 512) {
    int oc = t / 288, rem = t - oc * 288;
    int ic = rem / 9, tap = rem - ic * 9;
    wH1[(tap * 32 + (oc & 1) * 16 + (oc >> 1)) * 40 + ic] = __half_as_ushort(__float2half(c1w[t]));
  }
  __syncthreads();

  const int ic0 = lq * 8;
  f16x8 w1f[2][9];
#pragma unroll
  for (int ct = 0; ct < 2; ct++)
#pragma unroll
    for (int tap = 0; tap < 9; tap++)
      w1f[ct][tap] = *(const f16x8*)&wH1[(tap * 32 + ct * 16 + lr) * 40 + ic0];

  constexpr int OFF1[9] = {0, 8, 16, 288, 296, 304, 576, 584, 592};
  unsigned short* ybase = y1g + (size_t)img * 36992 + (lr >> 2) * 9248 + ((2 * lr) & 7);
  const unsigned short* inAg = inH + lq * 5472;
  for (int t = wv; t < 37; t += 8) {
    int m = t * 16 + lr;
    int ms = m < 577 ? m : 577;
    const unsigned short* ab = inAg + ((ms / 34) * 36 + (ms % 34)) * 8;
    f32x4 c0 = {0.f, 0.f, 0.f, 0.f}, c1v = {0.f, 0.f, 0.f, 0.f};
#pragma unroll
    for (int tap = 0; tap < 9; tap++) {
      f16x8 av = *(const f16x8*)(ab + OFF1[tap]);
      c0  = __builtin_amdgcn_mfma_f32_16x16x32_f16(av, w1f[0][tap], c0, 0, 0, 0);
      c1v = __builtin_amdgcn_mfma_f32_16x16x32_f16(av, w1f[1][tap], c1v, 0, 0, 0);
    }
#pragma unroll
    for (int r = 0; r < 4; r++) {
      int mo = t * 16 + lq * 4 + r;
      if (mo < 578) {
        unsigned u = (unsigned)__half_as_ushort(__float2half(c0[r]))
                   | ((unsigned)__half_as_ushort(__float2half(c1v[r])) << 16);
        *(unsigned*)(ybase + (h * 578 + mo) * 8) = u;
      }
    }
  }
}

// ------- conv2: IN1(stats from f16 y1)+relu + conv2 + IN2 + sigmoid -----------
// grid 1024 (one image); 512 thr; LDS: yB 73,984 + wH2 5,760 + statA/aL/cL 512 = 80,256 B.
__global__ __launch_bounds__(512, 4) void conv2_k(
    const unsigned short* __restrict__ y1g, const float* __restrict__ c2w,
    const float* __restrict__ g1, const float* __restrict__ b1,
    const float* __restrict__ g2, const float* __restrict__ b2,
    float* __restrict__ wout)
{
  extern __shared__ __align__(16) char smem[];
  unsigned short* yB  = (unsigned short*)smem;            // [g][1156][8] = 36,992 halves
  unsigned short* wH2 = (unsigned short*)(smem + 73984);  // [tap*8+oc][40]
  float* statA = (float*)(smem + 79744);                  // 64
  float* aL    = statA + 64;                              // 32
  float* cL    = aL + 32;                                 // 32
  float* transF = (float*)smem;                           // overlay [8][1032] post-conv2

  const int tid = threadIdx.x;
  const int wv = tid >> 6, ln = tid & 63;
  const int lr = ln & 15, lq = ln >> 4;
  const int p = blockIdx.x;

  if (tid < 64) statA[tid] = 0.f;

  // stage y1 image (contiguous, coalesced)
  const unsigned short* src = y1g + (size_t)p * 36992;
  for (int t = tid; t < 4624; t += 512)
    *(uint4*)&yB[t * 8] = *(const uint4*)(src + t * 8);
  for (int t = tid; t < 2304; t += 512) {
    int oc = t / 288, rem = t - oc * 288;
    int ic = rem / 9, tap = rem - ic * 9;
    wH2[(tap * 8 + oc) * 40 + ic] = __half_as_ushort(__float2half(c2w[t]));
  }
  __syncthreads();

  // IN1 stats from staged f16 (g = wv>>1; 2 waves per group)
  {
    int g = wv >> 1;
    float s[8], q[8];
#pragma unroll
    for (int e = 0; e < 8; e++) { s[e] = 0.f; q[e] = 0.f; }
    int base = (wv & 1) * 64 + ln;
    for (int k = 0; k < 10; k++) {
      int pix = base + 128 * k;
      if (pix < 1156) {
        f16x8 v = *(const f16x8*)&yB[g * 9248 + pix * 8];
#pragma unroll
        for (int e = 0; e < 8; e++) { float f = (float)v[e]; s[e] += f; q[e] += f * f; }
      }
    }
#pragma unroll
    for (int off = 1; off < 64; off <<= 1)
#pragma unroll
      for (int e = 0; e < 8; e++) { s[e] += __shfl_xor(s[e], off); q[e] += __shfl_xor(q[e], off); }
    if (ln == 0) {
#pragma unroll
      for (int e = 0; e < 8; e++) {
        atomicAdd(&statA[g * 8 + e], s[e]);
        atomicAdd(&statA[32 + g * 8 + e], q[e]);
      }
    }
  }
  __syncthreads();
  if (tid < 32) {
    float s = statA[tid], q = statA[32 + tid];
    float mu = s * (1.f / 1156.f);
    float var = q * (1.f / 1156.f) - mu * mu;
    float a_ = rsqrtf(var + 1e-5f) * g1[tid];
    aL[tid] = a_; cL[tid] = b1[tid] - mu * a_;
  }
  if (tid < 16) statA[tid] = 0.f;  // IN2 slots (own reads done above in program order)
  __syncthreads();

  // normalize + relu RMW
  {
    int g = tid >> 7, base = tid & 127;
    unsigned short* yg = yB + g * 9248;
    for (int k = 0; k < 10; k++) {
      int pix = base + 128 * k;
      if (pix < 1156) {
        f16x8 raw = *(const f16x8*)&yg[pix * 8];
        f16x8 outv;
#pragma unroll
        for (int e = 0; e < 8; e++) {
          float v = (float)raw[e];
          outv[e] = (_Float16)fmaxf(v * aL[g * 8 + e] + cL[g * 8 + e], 0.f);
        }
        *(f16x8*)&yg[pix * 8] = outv;
      }
    }
  }
  __syncthreads();

  // conv2 (8 tiles/wave), z kept in regs
  f16x8 w2f[9];
  const int ic0 = lq * 8;
#pragma unroll
  for (int tap = 0; tap < 9; tap++)
    w2f[tap] = *(const f16x8*)&wH2[(tap * 8 + (lr & 7)) * 40 + ic0];

  constexpr int OFF2[9] = {0, 8, 16, 272, 280, 288, 544, 552, 560};
  const unsigned short* yBg = yB + lq * 9248;
  f32x4 zsave[8];
  float s2 = 0.f, q2 = 0.f;
#pragma unroll
  for (int i = 0; i < 8; i++) {
    int t = wv + i * 8;
    int m = t * 16 + lr;
    const unsigned short* ab = yBg + ((m >> 5) * 34 + (m & 31)) * 8;
    f32x4 cc = {0.f, 0.f, 0.f, 0.f};
#pragma unroll
    for (int tap = 0; tap < 9; tap++) {
      f16x8 av = *(const f16x8*)(ab + OFF2[tap]);
      cc = __builtin_amdgcn_mfma_f32_16x16x32_f16(av, w2f[tap], cc, 0, 0, 0);
    }
    zsave[i] = cc;
#pragma unroll
    for (int r = 0; r < 4; r++) { s2 += cc[r]; q2 += cc[r] * cc[r]; }
  }
#pragma unroll
  for (int off = 16; off < 64; off <<= 1) {
    s2 += __shfl_xor(s2, off); q2 += __shfl_xor(q2, off);
  }
  if (ln < 8) { atomicAdd(&statA[ln], s2); atomicAdd(&statA[8 + ln], q2); }
  __syncthreads();   // all conv2 reads of yB done -> transF overlay safe; statA complete

  if (lr < 8) {
#pragma unroll
    for (int i = 0; i < 8; i++) {
      int t = wv + i * 8;
#pragma unroll
      for (int r = 0; r < 4; r++)
        transF[lr * 1032 + t * 16 + lq * 4 + r] = zsave[i][r];
    }
  }
  if (tid < 8) {
    float s = statA[tid], q = statA[8 + tid];
    float mu = s * (1.f / 1024.f);
    float var = q * (1.f / 1024.f) - mu * mu;
    float a_ = rsqrtf(var + 1e-5f) * g2[tid];
    aL[tid] = a_; cL[tid] = b2[tid] - mu * a_;
  }
  __syncthreads();

  for (int idx = tid; idx < 2048; idx += 512) {
    int oc = idx >> 8, p4 = (idx & 255) << 2;
    float4 v = *(const float4*)&transF[oc * 1032 + p4];
    float a_ = aL[oc], c_ = cL[oc];
    float4 o;
    o.x = 1.f / (1.f + __expf(-(v.x * a_ + c_)));
    o.y = 1.f / (1.f + __expf(-(v.y * a_ + c_)));
    o.z = 1.f / (1.f + __expf(-(v.z * a_ + c_)));
    o.w = 1.f / (1.f + __expf(-(v.w * a_ + c_)));
    *(float4*)(wout + ((size_t)oc << 20) + ((size_t)p << 10) + p4) = o;
  }
}

// ---------------- fused attention, bf16 MFMA 16x16x32 -------------------------
__global__ __launch_bounds__(256) void attn_kernel(
    const unsigned short* __restrict__ qkv,  // bf16 bits [8192][1536]
    const float* __restrict__ wppe,          // [8][1024][1024]
    float* __restrict__ oh)                  // [8192][512] = (b,n,h,d)
{
  __shared__ __align__(16) unsigned short k_lds[64 * 72];
  __shared__ __align__(16) unsigned short v_lds[64 * 72]; // transposed [d][m ^ swz]
  __shared__ __align__(16) unsigned short p_lds[4 * 16 * 72];
  const int tid = threadIdx.x;
  const int wv = tid >> 6, ln = tid & 63;
  const int lr = ln & 15, lq = ln >> 4;
  const int b = blockIdx.y >> 3, h = blockIdx.y & 7;
  const int n0 = blockIdx.x << 6;

  const size_t qoff = (size_t)((b << 10) + n0 + (wv << 4) + lr) * 1536 + (h << 6);
  bf16x8 qf0 = *(const bf16x8*)(qkv + qoff + lq * 8);
  bf16x8 qf1 = *(const bf16x8*)(qkv + qoff + 32 + lq * 8);

  f32x4 acc[4];
#pragma unroll
  for (int dt = 0; dt < 4; dt++) acc[dt] = (f32x4){0.f, 0.f, 0.f, 0.f};
  float den[4] = {0.f, 0.f, 0.f, 0.f};
  const float* wp = wppe + ((size_t)h << 20);

  for (int m0 = 0; m0 < 1024; m0 += 64) {
    __syncthreads();
    for (int t = tid; t < 512; t += 256) {
      int m = t >> 3, dq = t & 7;
      const unsigned short* kr = qkv + (size_t)((b << 10) + m0 + m) * 1536 + 512 + (h << 6) + dq * 8;
      *(uint4*)&k_lds[m * 72 + dq * 8] = *(const uint4*)kr;
      uint4 vvv = *(const uint4*)(kr + 512);
      unsigned short tmp[8];
      *(uint4*)tmp = vvv;
#pragma unroll
      for (int i = 0; i < 8; i++) {
        int d = dq * 8 + i;
        v_lds[d * 72 + (m ^ (((d >> 3) & 7) << 3))] = tmp[i];
      }
    }
    __syncthreads();

    f32x4 s[4];
#pragma unroll
    for (int mt = 0; mt < 4; mt++) {
      const unsigned short* kb = &k_lds[(mt * 16 + lr) * 72 + lq * 8];
      f32x4 cz = (f32x4){0.f, 0.f, 0.f, 0.f};
      cz = __builtin_amdgcn_mfma_f32_16x16x32_bf16(qf0, *(const bf16x8*)kb, cz, 0, 0, 0);
      cz = __builtin_amdgcn_mfma_f32_16x16x32_bf16(qf1, *(const bf16x8*)(kb + 32), cz, 0, 0, 0);
      s[mt] = cz;
    }
#pragma unroll
    for (int mt = 0; mt < 4; mt++)
#pragma unroll
      for (int reg = 0; reg < 4; reg++) {
        int rrow = lq * 4 + reg;
        float wvl = wp[(size_t)(n0 + (wv << 4) + rrow) * 1024 + (m0 + mt * 16 + lr)];
        float pv = wvl * __expf(s[mt][reg] * 0.125f);
        den[reg] += pv;
        p_lds[((wv << 4) + rrow) * 72 + mt * 16 + lr] = f2bf(pv);
      }
    const unsigned short* pb = &p_lds[((wv << 4) + lr) * 72];
    bf16x8 pa0 = *(const bf16x8*)(pb + lq * 8);
    bf16x8 pa1 = *(const bf16x8*)(pb + 32 + lq * 8);
#pragma unroll
    for (int dt = 0; dt < 4; dt++) {
      int d = dt * 16 + lr;
      int sw = ((d >> 3) & 7) << 3;
      const unsigned short* vb = &v_lds[d * 72];
      acc[dt] = __builtin_amdgcn_mfma_f32_16x16x32_bf16(pa0, *(const bf16x8*)(vb + ((lq * 8) ^ sw)), acc[dt], 0, 0, 0);
      acc[dt] = __builtin_amdgcn_mfma_f32_16x16x32_bf16(pa1, *(const bf16x8*)(vb + ((32 + lq * 8) ^ sw)), acc[dt], 0, 0, 0);
    }
  }
#pragma unroll
  for (int off = 1; off < 16; off <<= 1)
#pragma unroll
    for (int reg = 0; reg < 4; reg++) den[reg] += __shfl_xor(den[reg], off);
#pragma unroll
  for (int dt = 0; dt < 4; dt++)
#pragma unroll
    for (int reg = 0; reg < 4; reg++) {
      size_t row = (size_t)((b << 10) + n0 + (wv << 4) + lq * 4 + reg);
      oh[row * 512 + (h << 6) + dt * 16 + lr] = acc[dt][reg] / den[reg];
    }
}

// ---------------------------------------------------------------------------
extern "C" void kernel_launch(void* const* d_in, const int* in_sizes, int n_in,
                              void* d_out, int out_size, void* d_ws, size_t ws_size,
                              hipStream_t stream) {
  (void)in_sizes; (void)n_in; (void)out_size; (void)ws_size;
  const float* x     = (const float*)d_in[0];
  const float* rpe   = (const float*)d_in[1];
  const float* wqkv  = (const float*)d_in[2];
  const float* wproj = (const float*)d_in[3];
  const float* bproj = (const float*)d_in[4];
  const float* c1w   = (const float*)d_in[5];
  // d_in[6] = c1b: cancels exactly in the following instance-norm
  const float* g1w   = (const float*)d_in[7];
  const float* g1b   = (const float*)d_in[8];
  const float* c2w   = (const float*)d_in[9];
  // d_in[10] = c2b: cancels likewise
  const float* g2w   = (const float*)d_in[11];
  const float* g2b   = (const float*)d_in[12];
  float* out = (float*)d_out;

  char* ws = (char*)d_ws;
  unsigned short* qkv_bf = (unsigned short*)ws;            // 25,165,824 B
  float* wppe = (float*)(ws + 25165824);                   // 33,554,432 B
  unsigned short* y1g = (unsigned short*)(ws + 58720256);  // 75,759,616 B
  float* ohb  = (float*)(ws + 58720256);                   // overlays y1g (dead after conv2_k)

  // 1) qkv = x @ wqkv^T  -> bf16 (f16 MFMA)
  gemm_f16_bt<true><<<dim3(12, 64), 256, 0, stream>>>(x, wqkv, qkv_bf, nullptr, 8192, 1536, 512);

  // 2) conv1 -> y1g
  const int lds1 = 66816;
  hipFuncSetAttribute(reinterpret_cast<const void*>(&conv1_k),
                      hipFuncAttributeMaxDynamicSharedMemorySize, lds1);
  conv1_k<<<2048, 512, lds1, stream>>>(rpe, c1w, y1g);

  // 3) IN1+relu+conv2+IN2+sigmoid -> w
  const int lds2 = 80256;
  hipFuncSetAttribute(reinterpret_cast<const void*>(&conv2_k),
                      hipFuncAttributeMaxDynamicSharedMemorySize, lds2);
  conv2_k<<<1024, 512, lds2, stream>>>(y1g, c2w, g1w, g1b, g2w, g2b, wppe);

  // 4) fused attention
  attn_kernel<<<dim3(16, 64), 256, 0, stream>>>(qkv_bf, wppe, ohb);

  // 5) out = oh @ wproj^T + bproj (f16 MFMA)
  gemm_f16_bt<false><<<dim3(4, 64), 256, 0, stream>>>(ohb, wproj, out, bproj, 8192, 512, 512);
}